// Round 20
// baseline (348.212 us; speedup 1.0000x reference)
//
#include <hip/hip_runtime.h>

// Physics_Attention_1D: fused pipeline for MI355X (gfx950)
// Shapes: B=4, N=16384, D=256, H=8, DH=64, G=64, INNER=512
constexpr int B_ = 4;
constexpr int N_ = 16384;
constexpr int D_ = 256;
constexpr int H_ = 8;
constexpr int DH_ = 64;
constexpr int G_ = 64;
constexpr int INNER_ = 512;

typedef __attribute__((ext_vector_type(8))) short bf16x8;
typedef __attribute__((ext_vector_type(4))) float f32x4;

__device__ __forceinline__ unsigned short f2bu(float f) {
  union { float f; unsigned int u; } v; v.f = f;
  unsigned int r = v.u + 0x7FFFu + ((v.u >> 16) & 1u);  // RNE
  return (unsigned short)(r >> 16);
}
__device__ __forceinline__ float bu2f(unsigned short h) {
  union { unsigned int u; float f; } v; v.u = ((unsigned int)h) << 16;
  return v.f;
}
// gelu via branch-free Abramowitz-Stegun 7.1.26 erf (abs err 1.5e-7, << bf16 eps)
__device__ __forceinline__ float gelu_f(float x) {
  const float ax = fabsf(x);
  const float y = ax * 0.70710678118654752440f;
  const float t = 1.0f / fmaf(0.3275911f, y, 1.0f);
  float poly = 1.061405429f;
  poly = fmaf(poly, t, -1.453152027f);
  poly = fmaf(poly, t, 1.421413741f);
  poly = fmaf(poly, t, -0.284496736f);
  poly = fmaf(poly, t, 0.254829592f);
  poly *= t;
  const float e = __expf(-y * y);
  const float E = fmaf(-poly, e, 1.0f);
  return fmaf(0.5f * ax, E, 0.5f * x);
}

// ---------------------------------------------------------------- cast Wx -> bf16
__global__ __launch_bounds__(256) void cast_kernel(const float* __restrict__ in,
                                                   unsigned short* __restrict__ o, int n) {
  int i = (blockIdx.x * 256 + threadIdx.x) * 4;
  if (i + 3 < n) {
    float4 v = *reinterpret_cast<const float4*>(&in[i]);
    o[i + 0] = f2bu(v.x);
    o[i + 1] = f2bu(v.y);
    o[i + 2] = f2bu(v.z);
    o[i + 3] = f2bu(v.w);
  }
}

// ---------------------------------------------------------------- prep [W1;Ws] -> bf16 [128][64]
__global__ __launch_bounds__(256) void prep_wrb_kernel(const float* __restrict__ W1,
                                                       const float* __restrict__ Ws,
                                                       unsigned short* __restrict__ WrB) {
  const int i = blockIdx.x * 256 + threadIdx.x;
  if (i < 8192) {
    const int row = i >> 6, col = i & 63;
    const float v = (row < 64) ? W1[row * 64 + col] : Ws[(row - 64) * 64 + col];
    WrB[i] = f2bu(v);
  }
}

// ---------------------------------------------------------------- bf16 MFMA GEMM, C = A @ Bt^T (+bias)
// MODE 0: A = x (fp32, M=65536, K=256), Bt = Wx(bf16) [512x256], C = x_mid bf16 [M][512]
// MODE 1: A = w (bf16, per-batch M=16384, K=512), Bt = MT(bf16) [256x512], C = out fp32, batched over z=B
// LDS tiles padded to 72 cols (144 B rows): fragment ds_read_b128 off the 16-way pathology (verified r13).
template <int MODE>
__global__ __launch_bounds__(256)
void gemm_bt_kernel(const float* __restrict__ Af32,
                    const unsigned short* __restrict__ Abf,
                    const unsigned short* __restrict__ Bt,
                    unsigned short* __restrict__ Cbf,
                    float* __restrict__ Cf32,
                    const float* __restrict__ bias) {
  constexpr int K = (MODE == 0) ? 256 : 512;
  __shared__ unsigned short As[128][72];
  __shared__ unsigned short Bs[128][72];

  const int tid = threadIdx.x;
  const int lane = tid & 63;
  const int wid = tid >> 6;
  const int wm = wid >> 1;
  const int wn = wid & 1;
  const long m0 = (long)blockIdx.x * 128;
  const int n0 = blockIdx.y * 128;

  long aBase = 0, btBase = 0, cBase = 0;
  if constexpr (MODE == 1) {
    const long z = blockIdx.z;
    aBase = z * (long)N_ * 512;
    btBase = z * (long)D_ * 512;
    cBase = z * (long)N_ * D_;
  }

  f32x4 acc[4][4];
#pragma unroll
  for (int m = 0; m < 4; ++m)
#pragma unroll
    for (int n = 0; n < 4; ++n) acc[m][n] = (f32x4){0.f, 0.f, 0.f, 0.f};

  for (int t = 0; t < K / 64; ++t) {
    const int k0 = t * 64;
    if constexpr (MODE == 0) {
#pragma unroll
      for (int i = 0; i < 8; ++i) {
        const int flat = i * 1024 + tid * 4;
        const int r = flat >> 6;
        const int kk = flat & 63;
        const float4 v = *reinterpret_cast<const float4*>(&Af32[(m0 + r) * 256 + k0 + kk]);
        unsigned short tmp[4] = {f2bu(v.x), f2bu(v.y), f2bu(v.z), f2bu(v.w)};
        *reinterpret_cast<unsigned long long*>(&As[r][kk]) =
            *reinterpret_cast<unsigned long long*>(tmp);
      }
    } else {
#pragma unroll
      for (int i = 0; i < 4; ++i) {
        const int flat = i * 2048 + tid * 8;
        const int r = flat >> 6;
        const int kk = flat & 63;
        *reinterpret_cast<int4*>(&As[r][kk]) =
            *reinterpret_cast<const int4*>(&Abf[aBase + (m0 + r) * (long)K + k0 + kk]);
      }
    }
#pragma unroll
    for (int i = 0; i < 4; ++i) {
      const int flat = i * 2048 + tid * 8;
      const int c = flat >> 6;
      const int kk = flat & 63;
      *reinterpret_cast<int4*>(&Bs[c][kk]) =
          *reinterpret_cast<const int4*>(&Bt[btBase + (n0 + c) * (long)K + k0 + kk]);
    }
    __syncthreads();
#pragma unroll
    for (int kk = 0; kk < 2; ++kk) {
      bf16x8 a[4], bb[4];
#pragma unroll
      for (int m = 0; m < 4; ++m)
        a[m] = *reinterpret_cast<const bf16x8*>(
            &As[wm * 64 + m * 16 + (lane & 15)][kk * 32 + (lane >> 4) * 8]);
#pragma unroll
      for (int n = 0; n < 4; ++n)
        bb[n] = *reinterpret_cast<const bf16x8*>(
            &Bs[wn * 64 + n * 16 + (lane & 15)][kk * 32 + (lane >> 4) * 8]);
#pragma unroll
      for (int m = 0; m < 4; ++m)
#pragma unroll
        for (int n = 0; n < 4; ++n)
          acc[m][n] = __builtin_amdgcn_mfma_f32_16x16x32_bf16(a[m], bb[n], acc[m][n], 0, 0, 0);
    }
    __syncthreads();
  }
#pragma unroll
  for (int n = 0; n < 4; ++n) {
    const int c = n0 + wn * 64 + n * 16 + (lane & 15);
    const float bv = bias[c];
#pragma unroll
    for (int m = 0; m < 4; ++m) {
      const long rb = m0 + wm * 64 + m * 16 + ((lane >> 4) << 2);
#pragma unroll
      for (int j = 0; j < 4; ++j) {
        const float val = acc[m][n][j] + bv;
        if constexpr (MODE == 0) {
          Cbf[(rb + j) * 512 + c] = f2bu(val);
        } else {
          Cf32[cBase + (rb + j) * 256 + c] = val;
        }
      }
    }
  }
}

// ---------------------------------------------------------------- fused routing v9 = v8 (verified r15-r19)
// with Bs staging DELETED: WrB is a 16KB L2-resident constant shared by all 8192 blocks, so the
// 8 B-fragments are loaded directly global->registers at entry (latency hides under A staging).
// LDS drops 29.2KB -> ~18.5KB (union of As 9.2KB / hl 17.2KB) -> 8 blocks/CU for the VALU-bound
// phases (was 3). VGPR ~84, under the 128 cliff (r11 lesson: direct-global A was the failure,
// not broadcast-hot B).
__global__ __launch_bounds__(256)
void routing_fused_kernel(const unsigned short* __restrict__ xmid,
                          const unsigned short* __restrict__ WrB,
                          const float* __restrict__ u,
                          const float* __restrict__ b1,
                          const float* __restrict__ W2,
                          const float* __restrict__ b2,
                          const float* __restrict__ biasH,
                          const float* __restrict__ bs,
                          unsigned short* __restrict__ wout) {
  __shared__ union SM {
    unsigned short As[64][72];   // 9216 B
    float hl[64 * 67];           // 17152 B
  } sm;
  __shared__ float cw2[64], cb1[64], cbs[64], cbh[8];
  __shared__ float tempL[64];  // 1/temp per token row

  const int tid = threadIdx.x;
  const int lane = tid & 63;
  const int wid = tid >> 6;
  const int wm = wid >> 1;   // 32-row half
  const int wn = wid & 1;    // 64-col half (0: hidden, 1: logits)
  const int q = lane >> 4;
  const int c15 = lane & 15;

  if (tid < 64) {
    cw2[tid] = W2[tid];
    cb1[tid] = b1[tid];
    cbs[tid] = bs[tid];
  }
  if (tid < 8) cbh[tid] = biasH[tid];
  const float b2g = b2[0];

  // ---- B fragments straight from global (L2-hot 16 KB; same data every block)
  bf16x8 bfrag[2][4];
#pragma unroll
  for (int kk = 0; kk < 2; ++kk)
#pragma unroll
    for (int n = 0; n < 4; ++n)
      bfrag[kk][n] = *reinterpret_cast<const bf16x8*>(
          WrB + (wn * 64 + n * 16 + c15) * 64 + kk * 32 + q * 8);

  // ---- stage A (64 tokens x 64 ch) into padded rows
  const unsigned short* Ablk = xmid + (long)blockIdx.x * 4096;
#pragma unroll
  for (int i = 0; i < 2; ++i) {
    const int idx = i * 256 + tid;   // 512 int4 chunks
    const int row = idx >> 3;
    const int col = (idx & 7) * 8;
    *reinterpret_cast<int4*>(&sm.As[row][col]) = *reinterpret_cast<const int4*>(Ablk + idx * 8);
  }
  __syncthreads();

  f32x4 acc[2][4];
#pragma unroll
  for (int m = 0; m < 2; ++m)
#pragma unroll
    for (int n = 0; n < 4; ++n) acc[m][n] = (f32x4){0.f, 0.f, 0.f, 0.f};

#pragma unroll
  for (int kk = 0; kk < 2; ++kk) {
    bf16x8 a[2];
#pragma unroll
    for (int m = 0; m < 2; ++m)
      a[m] = *reinterpret_cast<const bf16x8*>(
          &sm.As[wm * 32 + m * 16 + c15][kk * 32 + q * 8]);
#pragma unroll
    for (int m = 0; m < 2; ++m)
#pragma unroll
      for (int n = 0; n < 4; ++n)
        acc[m][n] = __builtin_amdgcn_mfma_f32_16x16x32_bf16(a[m], bfrag[kk][n], acc[m][n], 0, 0, 0);
  }
  __syncthreads();  // staging consumed; LDS becomes hl

  // ---- phase B: hidden half (+b1) -> hl (acc dies here for hidden waves)
  if (wn == 0) {
    float b1v[4];
#pragma unroll
    for (int n = 0; n < 4; ++n) b1v[n] = cb1[n * 16 + c15];
#pragma unroll
    for (int m = 0; m < 2; ++m) {
      const int rb = wm * 32 + m * 16 + q * 4;
#pragma unroll
      for (int n = 0; n < 4; ++n) {
        const int c = n * 16 + c15;
#pragma unroll
        for (int j = 0; j < 4; ++j)
          sm.hl[(rb + j) * 67 + c] = acc[m][n][j] + b1v[n];
      }
    }
  }
  __syncthreads();

  // ---- phase C: temp-MLP finish, 4 threads/token (16 cols each)
  const int r_e = tid >> 2;        // 0..63
  const int quarter = tid & 3;
  const int g0 = quarter * 16;
  const long t_e = (long)blockIdx.x * 64 + r_e;
  const int h_e = (int)(t_e & 7);

  float sdot = 0.f;
#pragma unroll
  for (int j = 0; j < 16; ++j)
    sdot = fmaf(gelu_f(sm.hl[r_e * 67 + g0 + j]), cw2[g0 + j], sdot);
  sdot += __shfl_xor(sdot, 1);
  sdot += __shfl_xor(sdot, 2);
  if (quarter == 0) {
    float temp = gelu_f(sdot + b2g) + cbh[h_e];
    temp = fmaxf(temp, 0.01f);
    tempL[r_e] = 1.0f / temp;
  }
  __syncthreads();

  // ---- phase D: logits half (+bs) overwrite hl (acc dies here for logit waves)
  if (wn == 1) {
    float bsv[4];
#pragma unroll
    for (int n = 0; n < 4; ++n) bsv[n] = cbs[n * 16 + c15];
#pragma unroll
    for (int m = 0; m < 2; ++m) {
      const int rb = wm * 32 + m * 16 + q * 4;
#pragma unroll
      for (int n = 0; n < 4; ++n) {
        const int c = n * 16 + c15;
#pragma unroll
        for (int j = 0; j < 4; ++j)
          sm.hl[(rb + j) * 67 + c] = acc[m][n][j] + bsv[n];
      }
    }
  }
  __syncthreads();

  // ---- phase E: gumbel softmax, 4 threads/token, 16 g each
  const long bn_e = t_e >> 3;
  const long b_e = bn_e >> 14;
  const long n_e = bn_e & 16383;
  const long uoff = (((b_e * 8 + h_e) << 14) + n_e) * 64 + g0;

  const float inv_t = tempL[r_e];
  float sv[16];
  float mx = -1e30f;
#pragma unroll
  for (int q8 = 0; q8 < 4; ++q8) {
    const float4 uu = *reinterpret_cast<const float4*>(&u[uoff + q8 * 4]);
    const float ua[4] = {uu.x, uu.y, uu.z, uu.w};
#pragma unroll
    for (int e = 0; e < 4; ++e) {
      const int j = q8 * 4 + e;
      const float gn = -__logf(-__logf(ua[e] + 1e-8f) + 1e-8f);
      const float si = (sm.hl[r_e * 67 + g0 + j] + gn) * inv_t;
      sv[j] = si;
      mx = fmaxf(mx, si);
    }
  }
  mx = fmaxf(mx, __shfl_xor(mx, 1));
  mx = fmaxf(mx, __shfl_xor(mx, 2));
  float ssum = 0.f;
#pragma unroll
  for (int j = 0; j < 16; ++j) {
    const float e = __expf(sv[j] - mx);
    sv[j] = e;
    ssum += e;
  }
  ssum += __shfl_xor(ssum, 1);
  ssum += __shfl_xor(ssum, 2);
  const float inv_s = 1.0f / ssum;

  unsigned short* wrow = wout + t_e * 64 + g0;
#pragma unroll
  for (int i2 = 0; i2 < 2; ++i2) {
    unsigned short tmp[8];
#pragma unroll
    for (int j = 0; j < 8; ++j) tmp[j] = f2bu(sv[i2 * 8 + j] * inv_s);
    *reinterpret_cast<int4*>(wrow + i2 * 8) = *reinterpret_cast<const int4*>(tmp);
  }
}

// ---------------------------------------------------------------- pooling v5 (verified r18): non-atomic
// partials, grid 1024 = 32 bh x 32 chunks(512 tok), 8 sub-tiles of 64 tokens.
__global__ __launch_bounds__(256, 2)
void pool_v2_kernel(const unsigned short* __restrict__ xmid,
                    const unsigned short* __restrict__ wbf,
                    float* __restrict__ pacc, float* __restrict__ pnrm) {
  __shared__ __align__(16) float wl[64][68];
  __shared__ __align__(16) float xl[64][68];
  __shared__ float snl[64];
  const int tid = threadIdx.x;
  const int bx = blockIdx.x;
  const int bh = bx & 31;      // b*8 + h
  const int chunk = bx >> 5;   // 32 chunks of 512 tokens
  const int b = bh >> 3;
  const int h = bh & 7;
  // staging coords
  const int r = tid >> 2;          // token row 0..63
  const int p = (tid & 3) << 4;    // col 0,16,32,48
  // compute coords
  const int q = tid >> 6;          // group 0..3
  const int tin = tid & 63;
  const int gb = ((tin >> 3) & 7) << 3;  // 0,8,..,56
  const int cb = (tin & 7) << 3;         // 0,8,..,56

  float a[8][8];
#pragma unroll
  for (int gi = 0; gi < 8; ++gi)
#pragma unroll
    for (int ci = 0; ci < 8; ++ci) a[gi][ci] = 0.f;
  float sn[16];
#pragma unroll
  for (int j = 0; j < 16; ++j) sn[j] = 0.f;
  if (tid < 64) snl[tid] = 0.f;

  const long tok0 = (long)b * N_ + chunk * 512;

  for (int sub = 0; sub < 8; ++sub) {
    __syncthreads();  // previous tile fully consumed
    const long base = (tok0 + sub * 64 + r) * 512 + h * 64 + p;
    const int4 rw0 = *reinterpret_cast<const int4*>(&wbf[base]);
    const int4 rw1 = *reinterpret_cast<const int4*>(&wbf[base + 8]);
    const int4 rx0 = *reinterpret_cast<const int4*>(&xmid[base]);
    const int4 rx1 = *reinterpret_cast<const int4*>(&xmid[base + 8]);
    const unsigned short* pw0 = reinterpret_cast<const unsigned short*>(&rw0);
    const unsigned short* pw1 = reinterpret_cast<const unsigned short*>(&rw1);
    const unsigned short* px0 = reinterpret_cast<const unsigned short*>(&rx0);
    const unsigned short* px1 = reinterpret_cast<const unsigned short*>(&rx1);
#pragma unroll
    for (int j = 0; j < 8; ++j) {
      const float w0 = bu2f(pw0[j]);
      const float w1 = bu2f(pw1[j]);
      wl[r][p + j] = w0;
      wl[r][p + 8 + j] = w1;
      sn[j] += w0;
      sn[8 + j] += w1;
      xl[r][p + j] = bu2f(px0[j]);
      xl[r][p + 8 + j] = bu2f(px1[j]);
    }
    __syncthreads();
    for (int i = 0; i < 16; ++i) {
      const int nn = q * 16 + i;
      const f32x4 w0 = *reinterpret_cast<const f32x4*>(&wl[nn][gb]);
      const f32x4 w1 = *reinterpret_cast<const f32x4*>(&wl[nn][gb + 4]);
      const f32x4 x0 = *reinterpret_cast<const f32x4*>(&xl[nn][cb]);
      const f32x4 x1 = *reinterpret_cast<const f32x4*>(&xl[nn][cb + 4]);
      const float wv[8] = {w0[0], w0[1], w0[2], w0[3], w1[0], w1[1], w1[2], w1[3]};
      const float xv[8] = {x0[0], x0[1], x0[2], x0[3], x1[0], x1[1], x1[2], x1[3]};
#pragma unroll
      for (int gi = 0; gi < 8; ++gi)
#pragma unroll
        for (int ci = 0; ci < 8; ++ci) a[gi][ci] = fmaf(wv[gi], xv[ci], a[gi][ci]);
    }
  }

  // snrm partials into LDS
  __syncthreads();
#pragma unroll
  for (int j = 0; j < 16; ++j) atomicAdd(&snl[p + j], sn[j]);

  // merge the 4 replicated acc sets: conflict-free LDS passes (reuse wl/xl as flat f32)
  float* mA = &wl[0][0];  // 4352 f32 >= 4096
  float* mB = &xl[0][0];
  __syncthreads();
  if (q == 1 || q == 3) {
    float* mb = (q == 1) ? mA : mB;
#pragma unroll
    for (int gi = 0; gi < 8; ++gi)
#pragma unroll
      for (int ci = 0; ci < 8; ++ci) mb[(gi * 8 + ci) * 64 + tin] = a[gi][ci];
  }
  __syncthreads();
  if (q == 0) {
#pragma unroll
    for (int gi = 0; gi < 8; ++gi)
#pragma unroll
      for (int ci = 0; ci < 8; ++ci) a[gi][ci] += mA[(gi * 8 + ci) * 64 + tin];
  } else if (q == 2) {
#pragma unroll
    for (int gi = 0; gi < 8; ++gi)
#pragma unroll
      for (int ci = 0; ci < 8; ++ci) a[gi][ci] += mB[(gi * 8 + ci) * 64 + tin];
  }
  __syncthreads();
  if (q == 2) {
#pragma unroll
    for (int gi = 0; gi < 8; ++gi)
#pragma unroll
      for (int ci = 0; ci < 8; ++ci) mA[(gi * 8 + ci) * 64 + tin] = a[gi][ci];
  }
  __syncthreads();
  if (q == 0) {
    float* pblk = pacc + (long)bx * 4096;
#pragma unroll
    for (int gi = 0; gi < 8; ++gi) {
      float vals[8];
#pragma unroll
      for (int ci = 0; ci < 8; ++ci) vals[ci] = a[gi][ci] + mA[(gi * 8 + ci) * 64 + tin];
      *reinterpret_cast<float4*>(&pblk[(gb + gi) * 64 + cb]) =
          *reinterpret_cast<const float4*>(&vals[0]);
      *reinterpret_cast<float4*>(&pblk[(gb + gi) * 64 + cb + 4]) =
          *reinterpret_cast<const float4*>(&vals[4]);
    }
  }
  if (tid < 64) pnrm[(long)bx * 64 + tid] = snl[tid];
}

// ---------------------------------------------------------------- pool reduce: sacc[bh] = sum_chunks pacc
__global__ __launch_bounds__(256)
void pool_reduce_kernel(const float* __restrict__ pacc, const float* __restrict__ pnrm,
                        float* __restrict__ sacc, float* __restrict__ snrm) {
  const int bh = blockIdx.x;  // 0..31
  const int tid = threadIdx.x;
  float s[16];
#pragma unroll
  for (int i = 0; i < 16; ++i) s[i] = 0.f;
  for (int c = 0; c < 32; ++c) {
    const float* src = pacc + ((long)(c * 32 + bh)) * 4096 + tid * 16;
#pragma unroll
    for (int i = 0; i < 16; i += 4) {
      const float4 v = *reinterpret_cast<const float4*>(&src[i]);
      s[i] += v.x; s[i + 1] += v.y; s[i + 2] += v.z; s[i + 3] += v.w;
    }
  }
  float* dst = sacc + (long)bh * 4096 + tid * 16;
#pragma unroll
  for (int i = 0; i < 16; i += 4)
    *reinterpret_cast<float4*>(&dst[i]) = make_float4(s[i], s[i + 1], s[i + 2], s[i + 3]);
  if (tid < 64) {
    float t = 0.f;
    for (int c = 0; c < 32; ++c) t += pnrm[((long)(c * 32 + bh)) * 64 + tid];
    snrm[bh * 64 + tid] = t;
  }
}

// ---------------------------------------------------------------- slice attention core (fp32, tiny, ILP-4):
// computes out_s[b,h,g,c] -> outS scratch. MT build in its own parallel kernel.
__global__ __launch_bounds__(256)
void slice_attn_kernel(const float* __restrict__ sacc,
                       const float* __restrict__ snrm,
                       const float* __restrict__ Wq,
                       const float* __restrict__ Wk,
                       const float* __restrict__ Wv,
                       float* __restrict__ outS) {
  __shared__ float st[64][65];
  __shared__ float qq[64][65];
  __shared__ float kk_[64][65];
  __shared__ float vv[64][65];
  __shared__ float at[64][65];
  __shared__ float nrm[64];
  const int tid = threadIdx.x;
  const int bh = blockIdx.x;
  const int lane = tid & 63;
  const int w = tid >> 6;

  if (tid < 64) nrm[tid] = 1.0f / (snrm[bh * 64 + tid] + 1e-5f);
  __syncthreads();
#pragma unroll
  for (int i = 0; i < 16; ++i) {
    const int idx = tid * 16 + i;
    const int gg = idx >> 6;
    const int cc = idx & 63;
    st[gg][cc] = sacc[(long)bh * 4096 + idx] * nrm[gg];
  }
  __syncthreads();
  // q,k,v — ILP-4 dot chains
  for (int cc = 0; cc < 16; ++cc) {
    const int c = w * 16 + cc;
    const float* wqr = &Wq[c * 64];
    const float* wkr = &Wk[c * 64];
    const float* wvr = &Wv[c * 64];
    float q0 = 0.f, q1 = 0.f, q2 = 0.f, q3 = 0.f;
    float k0 = 0.f, k1 = 0.f, k2 = 0.f, k3 = 0.f;
    float v0 = 0.f, v1 = 0.f, v2 = 0.f, v3 = 0.f;
#pragma unroll
    for (int j = 0; j < 64; j += 4) {
      const float s0 = st[lane][j], s1 = st[lane][j + 1];
      const float s2 = st[lane][j + 2], s3 = st[lane][j + 3];
      q0 = fmaf(s0, wqr[j], q0); q1 = fmaf(s1, wqr[j + 1], q1);
      q2 = fmaf(s2, wqr[j + 2], q2); q3 = fmaf(s3, wqr[j + 3], q3);
      k0 = fmaf(s0, wkr[j], k0); k1 = fmaf(s1, wkr[j + 1], k1);
      k2 = fmaf(s2, wkr[j + 2], k2); k3 = fmaf(s3, wkr[j + 3], k3);
      v0 = fmaf(s0, wvr[j], v0); v1 = fmaf(s1, wvr[j + 1], v1);
      v2 = fmaf(s2, wvr[j + 2], v2); v3 = fmaf(s3, wvr[j + 3], v3);
    }
    qq[lane][c] = (q0 + q1) + (q2 + q3);
    kk_[lane][c] = (k0 + k1) + (k2 + k3);
    vv[lane][c] = (v0 + v1) + (v2 + v3);
  }
  __syncthreads();
  // attention logits — ILP-4
  for (int cc = 0; cc < 16; ++cc) {
    const int k2i = w * 16 + cc;
    float a0 = 0.f, a1 = 0.f, a2 = 0.f, a3 = 0.f;
#pragma unroll
    for (int j = 0; j < 64; j += 4) {
      a0 = fmaf(qq[lane][j], kk_[k2i][j], a0);
      a1 = fmaf(qq[lane][j + 1], kk_[k2i][j + 1], a1);
      a2 = fmaf(qq[lane][j + 2], kk_[k2i][j + 2], a2);
      a3 = fmaf(qq[lane][j + 3], kk_[k2i][j + 3], a3);
    }
    at[lane][k2i] = ((a0 + a1) + (a2 + a3)) * 0.125f;
  }
  __syncthreads();
  if (tid < 64) {
    float m0 = -1e30f, m1 = -1e30f, m2 = -1e30f, m3 = -1e30f;
#pragma unroll
    for (int j = 0; j < 64; j += 4) {
      m0 = fmaxf(m0, at[tid][j]); m1 = fmaxf(m1, at[tid][j + 1]);
      m2 = fmaxf(m2, at[tid][j + 2]); m3 = fmaxf(m3, at[tid][j + 3]);
    }
    const float m = fmaxf(fmaxf(m0, m1), fmaxf(m2, m3));
    float s0 = 0.f, s1 = 0.f, s2 = 0.f, s3 = 0.f;
#pragma unroll
    for (int j = 0; j < 64; j += 4) {
      const float e0 = __expf(at[tid][j] - m);
      const float e1 = __expf(at[tid][j + 1] - m);
      const float e2 = __expf(at[tid][j + 2] - m);
      const float e3 = __expf(at[tid][j + 3] - m);
      at[tid][j] = e0; at[tid][j + 1] = e1; at[tid][j + 2] = e2; at[tid][j + 3] = e3;
      s0 += e0; s1 += e1; s2 += e2; s3 += e3;
    }
    const float inv = 1.0f / ((s0 + s1) + (s2 + s3));
#pragma unroll
    for (int j = 0; j < 64; ++j) at[tid][j] *= inv;
  }
  __syncthreads();
  // out_s = attn @ v — ILP-4; write to outS scratch
  for (int cc = 0; cc < 16; ++cc) {
    const int c = w * 16 + cc;
    float a0 = 0.f, a1 = 0.f, a2 = 0.f, a3 = 0.f;
#pragma unroll
    for (int j = 0; j < 64; j += 4) {
      a0 = fmaf(at[lane][j], vv[j][c], a0);
      a1 = fmaf(at[lane][j + 1], vv[j + 1][c], a1);
      a2 = fmaf(at[lane][j + 2], vv[j + 2][c], a2);
      a3 = fmaf(at[lane][j + 3], vv[j + 3][c], a3);
    }
    outS[((long)bh * 64 + lane) * 64 + c] = (a0 + a1) + (a2 + a3);
  }
}

// ---------------------------------------------------------------- MT build (parallel, ILP-4):
// MT[b*256+d][h*64+g] = sum_c outS[((b*8+h)*64+g)*64+c] * Wo[d*512+h*64+c]
__global__ __launch_bounds__(256)
void mt_build_kernel(const float* __restrict__ outS, const float* __restrict__ Wo,
                     unsigned short* __restrict__ MT) {
  const int bd = blockIdx.x;   // b*256 + d
  const int b = bd >> 8;
  const int d = bd & 255;
  const int tid = threadIdx.x;
#pragma unroll
  for (int it = 0; it < 2; ++it) {
    const int hg = it * 256 + tid;
    const int h = hg >> 6;
    const int g = hg & 63;
    const float* wor = Wo + (long)d * 512 + h * 64;
    const float* os = outS + ((long)(b * 8 + h) * 64 + g) * 64;
    float a0 = 0.f, a1 = 0.f, a2 = 0.f, a3 = 0.f;
#pragma unroll
    for (int c = 0; c < 64; c += 4) {
      a0 = fmaf(os[c], wor[c], a0);
      a1 = fmaf(os[c + 1], wor[c + 1], a1);
      a2 = fmaf(os[c + 2], wor[c + 2], a2);
      a3 = fmaf(os[c + 3], wor[c + 3], a3);
    }
    MT[((long)b * 256 + d) * 512 + hg] = f2bu((a0 + a1) + (a2 + a3));
  }
}

// ---------------------------------------------------------------- launch
extern "C" void kernel_launch(void* const* d_in, const int* in_sizes, int n_in,
                              void* d_out, int out_size, void* d_ws, size_t ws_size,
                              hipStream_t stream) {
  const float* x = (const float*)d_in[0];
  const float* Wx = (const float*)d_in[1];
  const float* bx = (const float*)d_in[2];
  const float* W1 = (const float*)d_in[3];
  const float* b1 = (const float*)d_in[4];
  const float* W2 = (const float*)d_in[5];
  const float* b2 = (const float*)d_in[6];
  const float* bias = (const float*)d_in[7];
  const float* Ws = (const float*)d_in[8];
  const float* bs = (const float*)d_in[9];
  const float* Wq = (const float*)d_in[10];
  const float* Wk = (const float*)d_in[11];
  const float* Wv = (const float*)d_in[12];
  const float* Wo = (const float*)d_in[13];
  const float* bo = (const float*)d_in[14];
  const float* u = (const float*)d_in[15];
  float* out = (float*)d_out;

  char* ws = (char*)d_ws;
  unsigned short* xmid = (unsigned short*)(ws + 0);           // 67108864 B
  unsigned short* wbf = (unsigned short*)(ws + 67108864);     // 67108864 B
  float* sacc = (float*)(ws + 134217728);                     // 524288 B
  float* snrm = (float*)(ws + 134742016);                     // 8192 B
  unsigned short* Wxb = (unsigned short*)(ws + 134750208);    // 262144 B
  unsigned short* MT = (unsigned short*)(ws + 135012352);     // 1048576 B
  unsigned short* WrB = (unsigned short*)(ws + 136060928);    // 16384 B
  float* pacc = (float*)(ws + 136077312);                     // 16777216 B
  float* pnrm = (float*)(ws + 152854528);                     // 262144 B
  float* outS = (float*)(ws + 153116672);                     // 524288 B

  cast_kernel<<<dim3(128), dim3(256), 0, stream>>>(Wx, Wxb, INNER_ * D_);
  prep_wrb_kernel<<<dim3(32), dim3(256), 0, stream>>>(W1, Ws, WrB);
  gemm_bt_kernel<0><<<dim3(512, 4, 1), dim3(256), 0, stream>>>(x, nullptr, Wxb, xmid, nullptr, bx);
  routing_fused_kernel<<<dim3(8192), dim3(256), 0, stream>>>(xmid, WrB, u, b1, W2, b2, bias, bs, wbf);
  pool_v2_kernel<<<dim3(1024), dim3(256), 0, stream>>>(xmid, wbf, pacc, pnrm);
  pool_reduce_kernel<<<dim3(32), dim3(256), 0, stream>>>(pacc, pnrm, sacc, snrm);
  slice_attn_kernel<<<dim3(32), dim3(256), 0, stream>>>(sacc, snrm, Wq, Wk, Wv, outS);
  mt_build_kernel<<<dim3(1024), dim3(256), 0, stream>>>(outS, Wo, MT);
  gemm_bt_kernel<1><<<dim3(128, 2, 4), dim3(256), 0, stream>>>(nullptr, wbf, MT, nullptr, out, bo);
}

// Round 21
// 346.511 us; speedup vs baseline: 1.0049x; 1.0049x over previous
//
#include <hip/hip_runtime.h>

// Physics_Attention_1D: fused pipeline for MI355X (gfx950)
// Shapes: B=4, N=16384, D=256, H=8, DH=64, G=64, INNER=512
constexpr int B_ = 4;
constexpr int N_ = 16384;
constexpr int D_ = 256;
constexpr int H_ = 8;
constexpr int DH_ = 64;
constexpr int G_ = 64;
constexpr int INNER_ = 512;

typedef __attribute__((ext_vector_type(8))) short bf16x8;
typedef __attribute__((ext_vector_type(4))) float f32x4;

__device__ __forceinline__ unsigned short f2bu(float f) {
  union { float f; unsigned int u; } v; v.f = f;
  unsigned int r = v.u + 0x7FFFu + ((v.u >> 16) & 1u);  // RNE
  return (unsigned short)(r >> 16);
}
__device__ __forceinline__ float bu2f(unsigned short h) {
  union { unsigned int u; float f; } v; v.u = ((unsigned int)h) << 16;
  return v.f;
}
// gelu via branch-free Abramowitz-Stegun 7.1.26 erf (abs err 1.5e-7, << bf16 eps)
__device__ __forceinline__ float gelu_f(float x) {
  const float ax = fabsf(x);
  const float y = ax * 0.70710678118654752440f;
  const float t = 1.0f / fmaf(0.3275911f, y, 1.0f);
  float poly = 1.061405429f;
  poly = fmaf(poly, t, -1.453152027f);
  poly = fmaf(poly, t, 1.421413741f);
  poly = fmaf(poly, t, -0.284496736f);
  poly = fmaf(poly, t, 0.254829592f);
  poly *= t;
  const float e = __expf(-y * y);
  const float E = fmaf(-poly, e, 1.0f);
  return fmaf(0.5f * ax, E, 0.5f * x);
}

// ---------------------------------------------------------------- cast Wx -> bf16
__global__ __launch_bounds__(256) void cast_kernel(const float* __restrict__ in,
                                                   unsigned short* __restrict__ o, int n) {
  int i = (blockIdx.x * 256 + threadIdx.x) * 4;
  if (i + 3 < n) {
    float4 v = *reinterpret_cast<const float4*>(&in[i]);
    o[i + 0] = f2bu(v.x);
    o[i + 1] = f2bu(v.y);
    o[i + 2] = f2bu(v.z);
    o[i + 3] = f2bu(v.w);
  }
}

// ---------------------------------------------------------------- prep [W1;Ws] -> bf16 [128][64]
__global__ __launch_bounds__(256) void prep_wrb_kernel(const float* __restrict__ W1,
                                                       const float* __restrict__ Ws,
                                                       unsigned short* __restrict__ WrB) {
  const int i = blockIdx.x * 256 + threadIdx.x;
  if (i < 8192) {
    const int row = i >> 6, col = i & 63;
    const float v = (row < 64) ? W1[row * 64 + col] : Ws[(row - 64) * 64 + col];
    WrB[i] = f2bu(v);
  }
}

// ---------------------------------------------------------------- bf16 MFMA GEMM, C = A @ Bt^T (+bias)
// MODE 0: A = x (fp32, M=65536, K=256), Bt = Wx(bf16) [512x256], C = x_mid bf16 [M][512]
// MODE 1: A = w (bf16, per-batch M=16384, K=512), Bt = MT(bf16) [256x512], C = out fp32, batched over z=B
// LDS tiles padded to 72 cols (144 B rows): fragment ds_read_b128 off the 16-way pathology (verified r13).
template <int MODE>
__global__ __launch_bounds__(256)
void gemm_bt_kernel(const float* __restrict__ Af32,
                    const unsigned short* __restrict__ Abf,
                    const unsigned short* __restrict__ Bt,
                    unsigned short* __restrict__ Cbf,
                    float* __restrict__ Cf32,
                    const float* __restrict__ bias) {
  constexpr int K = (MODE == 0) ? 256 : 512;
  __shared__ unsigned short As[128][72];
  __shared__ unsigned short Bs[128][72];

  const int tid = threadIdx.x;
  const int lane = tid & 63;
  const int wid = tid >> 6;
  const int wm = wid >> 1;
  const int wn = wid & 1;
  const long m0 = (long)blockIdx.x * 128;
  const int n0 = blockIdx.y * 128;

  long aBase = 0, btBase = 0, cBase = 0;
  if constexpr (MODE == 1) {
    const long z = blockIdx.z;
    aBase = z * (long)N_ * 512;
    btBase = z * (long)D_ * 512;
    cBase = z * (long)N_ * D_;
  }

  f32x4 acc[4][4];
#pragma unroll
  for (int m = 0; m < 4; ++m)
#pragma unroll
    for (int n = 0; n < 4; ++n) acc[m][n] = (f32x4){0.f, 0.f, 0.f, 0.f};

  for (int t = 0; t < K / 64; ++t) {
    const int k0 = t * 64;
    if constexpr (MODE == 0) {
#pragma unroll
      for (int i = 0; i < 8; ++i) {
        const int flat = i * 1024 + tid * 4;
        const int r = flat >> 6;
        const int kk = flat & 63;
        const float4 v = *reinterpret_cast<const float4*>(&Af32[(m0 + r) * 256 + k0 + kk]);
        unsigned short tmp[4] = {f2bu(v.x), f2bu(v.y), f2bu(v.z), f2bu(v.w)};
        *reinterpret_cast<unsigned long long*>(&As[r][kk]) =
            *reinterpret_cast<unsigned long long*>(tmp);
      }
    } else {
#pragma unroll
      for (int i = 0; i < 4; ++i) {
        const int flat = i * 2048 + tid * 8;
        const int r = flat >> 6;
        const int kk = flat & 63;
        *reinterpret_cast<int4*>(&As[r][kk]) =
            *reinterpret_cast<const int4*>(&Abf[aBase + (m0 + r) * (long)K + k0 + kk]);
      }
    }
#pragma unroll
    for (int i = 0; i < 4; ++i) {
      const int flat = i * 2048 + tid * 8;
      const int c = flat >> 6;
      const int kk = flat & 63;
      *reinterpret_cast<int4*>(&Bs[c][kk]) =
          *reinterpret_cast<const int4*>(&Bt[btBase + (n0 + c) * (long)K + k0 + kk]);
    }
    __syncthreads();
#pragma unroll
    for (int kk = 0; kk < 2; ++kk) {
      bf16x8 a[4], bb[4];
#pragma unroll
      for (int m = 0; m < 4; ++m)
        a[m] = *reinterpret_cast<const bf16x8*>(
            &As[wm * 64 + m * 16 + (lane & 15)][kk * 32 + (lane >> 4) * 8]);
#pragma unroll
      for (int n = 0; n < 4; ++n)
        bb[n] = *reinterpret_cast<const bf16x8*>(
            &Bs[wn * 64 + n * 16 + (lane & 15)][kk * 32 + (lane >> 4) * 8]);
#pragma unroll
      for (int m = 0; m < 4; ++m)
#pragma unroll
        for (int n = 0; n < 4; ++n)
          acc[m][n] = __builtin_amdgcn_mfma_f32_16x16x32_bf16(a[m], bb[n], acc[m][n], 0, 0, 0);
    }
    __syncthreads();
  }
#pragma unroll
  for (int n = 0; n < 4; ++n) {
    const int c = n0 + wn * 64 + n * 16 + (lane & 15);
    const float bv = bias[c];
#pragma unroll
    for (int m = 0; m < 4; ++m) {
      const long rb = m0 + wm * 64 + m * 16 + ((lane >> 4) << 2);
#pragma unroll
      for (int j = 0; j < 4; ++j) {
        const float val = acc[m][n][j] + bv;
        if constexpr (MODE == 0) {
          Cbf[(rb + j) * 512 + c] = f2bu(val);
        } else {
          Cf32[cBase + (rb + j) * 256 + c] = val;
        }
      }
    }
  }
}

// ---------------------------------------------------------------- fused routing v10 = v9 with phases B and D
// MERGED: hidden and logit halves get SEPARATE LDS buffers (hl1, hl2) so both wave-halves write
// simultaneously — removes the structural half-idle (VALUBusy ceiling 72% = 0.75 phase activity)
// and one barrier. LDS ~36.5KB -> 4 blocks/CU (still ample for a VALU-bound kernel).
__global__ __launch_bounds__(256)
void routing_fused_kernel(const unsigned short* __restrict__ xmid,
                          const unsigned short* __restrict__ WrB,
                          const float* __restrict__ u,
                          const float* __restrict__ b1,
                          const float* __restrict__ W2,
                          const float* __restrict__ b2,
                          const float* __restrict__ biasH,
                          const float* __restrict__ bs,
                          unsigned short* __restrict__ wout) {
  __shared__ union SM {
    unsigned short As[64][72];   // 9216 B (dies before hl1 is written)
    float hl1[64 * 67];          // 17152 B — hidden
  } sm;
  __shared__ float hl2[64 * 67];  // 17152 B — logits
  __shared__ float cw2[64], cb1[64], cbs[64], cbh[8];
  __shared__ float tempL[64];  // 1/temp per token row

  const int tid = threadIdx.x;
  const int lane = tid & 63;
  const int wid = tid >> 6;
  const int wm = wid >> 1;   // 32-row half
  const int wn = wid & 1;    // 64-col half (0: hidden, 1: logits)
  const int q = lane >> 4;
  const int c15 = lane & 15;

  if (tid < 64) {
    cw2[tid] = W2[tid];
    cb1[tid] = b1[tid];
    cbs[tid] = bs[tid];
  }
  if (tid < 8) cbh[tid] = biasH[tid];
  const float b2g = b2[0];

  // ---- B fragments straight from global (L2-hot 16 KB; same data every block)
  bf16x8 bfrag[2][4];
#pragma unroll
  for (int kk = 0; kk < 2; ++kk)
#pragma unroll
    for (int n = 0; n < 4; ++n)
      bfrag[kk][n] = *reinterpret_cast<const bf16x8*>(
          WrB + (wn * 64 + n * 16 + c15) * 64 + kk * 32 + q * 8);

  // ---- stage A (64 tokens x 64 ch) into padded rows
  const unsigned short* Ablk = xmid + (long)blockIdx.x * 4096;
#pragma unroll
  for (int i = 0; i < 2; ++i) {
    const int idx = i * 256 + tid;   // 512 int4 chunks
    const int row = idx >> 3;
    const int col = (idx & 7) * 8;
    *reinterpret_cast<int4*>(&sm.As[row][col]) = *reinterpret_cast<const int4*>(Ablk + idx * 8);
  }
  __syncthreads();

  f32x4 acc[2][4];
#pragma unroll
  for (int m = 0; m < 2; ++m)
#pragma unroll
    for (int n = 0; n < 4; ++n) acc[m][n] = (f32x4){0.f, 0.f, 0.f, 0.f};

#pragma unroll
  for (int kk = 0; kk < 2; ++kk) {
    bf16x8 a[2];
#pragma unroll
    for (int m = 0; m < 2; ++m)
      a[m] = *reinterpret_cast<const bf16x8*>(
          &sm.As[wm * 32 + m * 16 + c15][kk * 32 + q * 8]);
#pragma unroll
    for (int m = 0; m < 2; ++m)
#pragma unroll
      for (int n = 0; n < 4; ++n)
        acc[m][n] = __builtin_amdgcn_mfma_f32_16x16x32_bf16(a[m], bfrag[kk][n], acc[m][n], 0, 0, 0);
  }
  __syncthreads();  // staging consumed; sm becomes hl1

  // ---- phase B' (merged): ALL waves write. wn==0 -> hl1 (+b1), wn==1 -> hl2 (+bs)
  {
    float bv[4];
    float* dst = (wn == 0) ? sm.hl1 : hl2;
    const float* bsrc = (wn == 0) ? cb1 : cbs;
#pragma unroll
    for (int n = 0; n < 4; ++n) bv[n] = bsrc[n * 16 + c15];
#pragma unroll
    for (int m = 0; m < 2; ++m) {
      const int rb = wm * 32 + m * 16 + q * 4;
#pragma unroll
      for (int n = 0; n < 4; ++n) {
        const int c = n * 16 + c15;
#pragma unroll
        for (int j = 0; j < 4; ++j)
          dst[(rb + j) * 67 + c] = acc[m][n][j] + bv[n];
      }
    }
  }
  __syncthreads();

  // ---- phase C: temp-MLP finish, 4 threads/token (16 cols each), reads hl1
  const int r_e = tid >> 2;        // 0..63
  const int quarter = tid & 3;
  const int g0 = quarter * 16;
  const long t_e = (long)blockIdx.x * 64 + r_e;
  const int h_e = (int)(t_e & 7);

  float sdot = 0.f;
#pragma unroll
  for (int j = 0; j < 16; ++j)
    sdot = fmaf(gelu_f(sm.hl1[r_e * 67 + g0 + j]), cw2[g0 + j], sdot);
  sdot += __shfl_xor(sdot, 1);
  sdot += __shfl_xor(sdot, 2);
  if (quarter == 0) {
    float temp = gelu_f(sdot + b2g) + cbh[h_e];
    temp = fmaxf(temp, 0.01f);
    tempL[r_e] = 1.0f / temp;
  }
  __syncthreads();

  // ---- phase E: gumbel softmax, 4 threads/token, 16 g each, reads hl2 + tempL
  const long bn_e = t_e >> 3;
  const long b_e = bn_e >> 14;
  const long n_e = bn_e & 16383;
  const long uoff = (((b_e * 8 + h_e) << 14) + n_e) * 64 + g0;

  const float inv_t = tempL[r_e];
  float sv[16];
  float mx = -1e30f;
#pragma unroll
  for (int q8 = 0; q8 < 4; ++q8) {
    const float4 uu = *reinterpret_cast<const float4*>(&u[uoff + q8 * 4]);
    const float ua[4] = {uu.x, uu.y, uu.z, uu.w};
#pragma unroll
    for (int e = 0; e < 4; ++e) {
      const int j = q8 * 4 + e;
      const float gn = -__logf(-__logf(ua[e] + 1e-8f) + 1e-8f);
      const float si = (hl2[r_e * 67 + g0 + j] + gn) * inv_t;
      sv[j] = si;
      mx = fmaxf(mx, si);
    }
  }
  mx = fmaxf(mx, __shfl_xor(mx, 1));
  mx = fmaxf(mx, __shfl_xor(mx, 2));
  float ssum = 0.f;
#pragma unroll
  for (int j = 0; j < 16; ++j) {
    const float e = __expf(sv[j] - mx);
    sv[j] = e;
    ssum += e;
  }
  ssum += __shfl_xor(ssum, 1);
  ssum += __shfl_xor(ssum, 2);
  const float inv_s = 1.0f / ssum;

  unsigned short* wrow = wout + t_e * 64 + g0;
#pragma unroll
  for (int i2 = 0; i2 < 2; ++i2) {
    unsigned short tmp[8];
#pragma unroll
    for (int j = 0; j < 8; ++j) tmp[j] = f2bu(sv[i2 * 8 + j] * inv_s);
    *reinterpret_cast<int4*>(wrow + i2 * 8) = *reinterpret_cast<const int4*>(tmp);
  }
}

// ---------------------------------------------------------------- pooling v5 (verified r18): non-atomic
// partials, grid 1024 = 32 bh x 32 chunks(512 tok), 8 sub-tiles of 64 tokens.
__global__ __launch_bounds__(256, 2)
void pool_v2_kernel(const unsigned short* __restrict__ xmid,
                    const unsigned short* __restrict__ wbf,
                    float* __restrict__ pacc, float* __restrict__ pnrm) {
  __shared__ __align__(16) float wl[64][68];
  __shared__ __align__(16) float xl[64][68];
  __shared__ float snl[64];
  const int tid = threadIdx.x;
  const int bx = blockIdx.x;
  const int bh = bx & 31;      // b*8 + h
  const int chunk = bx >> 5;   // 32 chunks of 512 tokens
  const int b = bh >> 3;
  const int h = bh & 7;
  // staging coords
  const int r = tid >> 2;          // token row 0..63
  const int p = (tid & 3) << 4;    // col 0,16,32,48
  // compute coords
  const int q = tid >> 6;          // group 0..3
  const int tin = tid & 63;
  const int gb = ((tin >> 3) & 7) << 3;  // 0,8,..,56
  const int cb = (tin & 7) << 3;         // 0,8,..,56

  float a[8][8];
#pragma unroll
  for (int gi = 0; gi < 8; ++gi)
#pragma unroll
    for (int ci = 0; ci < 8; ++ci) a[gi][ci] = 0.f;
  float sn[16];
#pragma unroll
  for (int j = 0; j < 16; ++j) sn[j] = 0.f;
  if (tid < 64) snl[tid] = 0.f;

  const long tok0 = (long)b * N_ + chunk * 512;

  for (int sub = 0; sub < 8; ++sub) {
    __syncthreads();  // previous tile fully consumed
    const long base = (tok0 + sub * 64 + r) * 512 + h * 64 + p;
    const int4 rw0 = *reinterpret_cast<const int4*>(&wbf[base]);
    const int4 rw1 = *reinterpret_cast<const int4*>(&wbf[base + 8]);
    const int4 rx0 = *reinterpret_cast<const int4*>(&xmid[base]);
    const int4 rx1 = *reinterpret_cast<const int4*>(&xmid[base + 8]);
    const unsigned short* pw0 = reinterpret_cast<const unsigned short*>(&rw0);
    const unsigned short* pw1 = reinterpret_cast<const unsigned short*>(&rw1);
    const unsigned short* px0 = reinterpret_cast<const unsigned short*>(&rx0);
    const unsigned short* px1 = reinterpret_cast<const unsigned short*>(&rx1);
#pragma unroll
    for (int j = 0; j < 8; ++j) {
      const float w0 = bu2f(pw0[j]);
      const float w1 = bu2f(pw1[j]);
      wl[r][p + j] = w0;
      wl[r][p + 8 + j] = w1;
      sn[j] += w0;
      sn[8 + j] += w1;
      xl[r][p + j] = bu2f(px0[j]);
      xl[r][p + 8 + j] = bu2f(px1[j]);
    }
    __syncthreads();
    for (int i = 0; i < 16; ++i) {
      const int nn = q * 16 + i;
      const f32x4 w0 = *reinterpret_cast<const f32x4*>(&wl[nn][gb]);
      const f32x4 w1 = *reinterpret_cast<const f32x4*>(&wl[nn][gb + 4]);
      const f32x4 x0 = *reinterpret_cast<const f32x4*>(&xl[nn][cb]);
      const f32x4 x1 = *reinterpret_cast<const f32x4*>(&xl[nn][cb + 4]);
      const float wv[8] = {w0[0], w0[1], w0[2], w0[3], w1[0], w1[1], w1[2], w1[3]};
      const float xv[8] = {x0[0], x0[1], x0[2], x0[3], x1[0], x1[1], x1[2], x1[3]};
#pragma unroll
      for (int gi = 0; gi < 8; ++gi)
#pragma unroll
        for (int ci = 0; ci < 8; ++ci) a[gi][ci] = fmaf(wv[gi], xv[ci], a[gi][ci]);
    }
  }

  // snrm partials into LDS
  __syncthreads();
#pragma unroll
  for (int j = 0; j < 16; ++j) atomicAdd(&snl[p + j], sn[j]);

  // merge the 4 replicated acc sets: conflict-free LDS passes (reuse wl/xl as flat f32)
  float* mA = &wl[0][0];  // 4352 f32 >= 4096
  float* mB = &xl[0][0];
  __syncthreads();
  if (q == 1 || q == 3) {
    float* mb = (q == 1) ? mA : mB;
#pragma unroll
    for (int gi = 0; gi < 8; ++gi)
#pragma unroll
      for (int ci = 0; ci < 8; ++ci) mb[(gi * 8 + ci) * 64 + tin] = a[gi][ci];
  }
  __syncthreads();
  if (q == 0) {
#pragma unroll
    for (int gi = 0; gi < 8; ++gi)
#pragma unroll
      for (int ci = 0; ci < 8; ++ci) a[gi][ci] += mA[(gi * 8 + ci) * 64 + tin];
  } else if (q == 2) {
#pragma unroll
    for (int gi = 0; gi < 8; ++gi)
#pragma unroll
      for (int ci = 0; ci < 8; ++ci) a[gi][ci] += mB[(gi * 8 + ci) * 64 + tin];
  }
  __syncthreads();
  if (q == 2) {
#pragma unroll
    for (int gi = 0; gi < 8; ++gi)
#pragma unroll
      for (int ci = 0; ci < 8; ++ci) mA[(gi * 8 + ci) * 64 + tin] = a[gi][ci];
  }
  __syncthreads();
  if (q == 0) {
    float* pblk = pacc + (long)bx * 4096;
#pragma unroll
    for (int gi = 0; gi < 8; ++gi) {
      float vals[8];
#pragma unroll
      for (int ci = 0; ci < 8; ++ci) vals[ci] = a[gi][ci] + mA[(gi * 8 + ci) * 64 + tin];
      *reinterpret_cast<float4*>(&pblk[(gb + gi) * 64 + cb]) =
          *reinterpret_cast<const float4*>(&vals[0]);
      *reinterpret_cast<float4*>(&pblk[(gb + gi) * 64 + cb + 4]) =
          *reinterpret_cast<const float4*>(&vals[4]);
    }
  }
  if (tid < 64) pnrm[(long)bx * 64 + tid] = snl[tid];
}

// ---------------------------------------------------------------- pool reduce: sacc[bh] = sum_chunks pacc
__global__ __launch_bounds__(256)
void pool_reduce_kernel(const float* __restrict__ pacc, const float* __restrict__ pnrm,
                        float* __restrict__ sacc, float* __restrict__ snrm) {
  const int bh = blockIdx.x;  // 0..31
  const int tid = threadIdx.x;
  float s[16];
#pragma unroll
  for (int i = 0; i < 16; ++i) s[i] = 0.f;
  for (int c = 0; c < 32; ++c) {
    const float* src = pacc + ((long)(c * 32 + bh)) * 4096 + tid * 16;
#pragma unroll
    for (int i = 0; i < 16; i += 4) {
      const float4 v = *reinterpret_cast<const float4*>(&src[i]);
      s[i] += v.x; s[i + 1] += v.y; s[i + 2] += v.z; s[i + 3] += v.w;
    }
  }
  float* dst = sacc + (long)bh * 4096 + tid * 16;
#pragma unroll
  for (int i = 0; i < 16; i += 4)
    *reinterpret_cast<float4*>(&dst[i]) = make_float4(s[i], s[i + 1], s[i + 2], s[i + 3]);
  if (tid < 64) {
    float t = 0.f;
    for (int c = 0; c < 32; ++c) t += pnrm[((long)(c * 32 + bh)) * 64 + tid];
    snrm[bh * 64 + tid] = t;
  }
}

// ---------------------------------------------------------------- slice attention core (fp32, tiny, ILP-4):
// computes out_s[b,h,g,c] -> outS scratch. MT build in its own parallel kernel.
__global__ __launch_bounds__(256)
void slice_attn_kernel(const float* __restrict__ sacc,
                       const float* __restrict__ snrm,
                       const float* __restrict__ Wq,
                       const float* __restrict__ Wk,
                       const float* __restrict__ Wv,
                       float* __restrict__ outS) {
  __shared__ float st[64][65];
  __shared__ float qq[64][65];
  __shared__ float kk_[64][65];
  __shared__ float vv[64][65];
  __shared__ float at[64][65];
  __shared__ float nrm[64];
  const int tid = threadIdx.x;
  const int bh = blockIdx.x;
  const int lane = tid & 63;
  const int w = tid >> 6;

  if (tid < 64) nrm[tid] = 1.0f / (snrm[bh * 64 + tid] + 1e-5f);
  __syncthreads();
#pragma unroll
  for (int i = 0; i < 16; ++i) {
    const int idx = tid * 16 + i;
    const int gg = idx >> 6;
    const int cc = idx & 63;
    st[gg][cc] = sacc[(long)bh * 4096 + idx] * nrm[gg];
  }
  __syncthreads();
  // q,k,v — ILP-4 dot chains
  for (int cc = 0; cc < 16; ++cc) {
    const int c = w * 16 + cc;
    const float* wqr = &Wq[c * 64];
    const float* wkr = &Wk[c * 64];
    const float* wvr = &Wv[c * 64];
    float q0 = 0.f, q1 = 0.f, q2 = 0.f, q3 = 0.f;
    float k0 = 0.f, k1 = 0.f, k2 = 0.f, k3 = 0.f;
    float v0 = 0.f, v1 = 0.f, v2 = 0.f, v3 = 0.f;
#pragma unroll
    for (int j = 0; j < 64; j += 4) {
      const float s0 = st[lane][j], s1 = st[lane][j + 1];
      const float s2 = st[lane][j + 2], s3 = st[lane][j + 3];
      q0 = fmaf(s0, wqr[j], q0); q1 = fmaf(s1, wqr[j + 1], q1);
      q2 = fmaf(s2, wqr[j + 2], q2); q3 = fmaf(s3, wqr[j + 3], q3);
      k0 = fmaf(s0, wkr[j], k0); k1 = fmaf(s1, wkr[j + 1], k1);
      k2 = fmaf(s2, wkr[j + 2], k2); k3 = fmaf(s3, wkr[j + 3], k3);
      v0 = fmaf(s0, wvr[j], v0); v1 = fmaf(s1, wvr[j + 1], v1);
      v2 = fmaf(s2, wvr[j + 2], v2); v3 = fmaf(s3, wvr[j + 3], v3);
    }
    qq[lane][c] = (q0 + q1) + (q2 + q3);
    kk_[lane][c] = (k0 + k1) + (k2 + k3);
    vv[lane][c] = (v0 + v1) + (v2 + v3);
  }
  __syncthreads();
  // attention logits — ILP-4
  for (int cc = 0; cc < 16; ++cc) {
    const int k2i = w * 16 + cc;
    float a0 = 0.f, a1 = 0.f, a2 = 0.f, a3 = 0.f;
#pragma unroll
    for (int j = 0; j < 64; j += 4) {
      a0 = fmaf(qq[lane][j], kk_[k2i][j], a0);
      a1 = fmaf(qq[lane][j + 1], kk_[k2i][j + 1], a1);
      a2 = fmaf(qq[lane][j + 2], kk_[k2i][j + 2], a2);
      a3 = fmaf(qq[lane][j + 3], kk_[k2i][j + 3], a3);
    }
    at[lane][k2i] = ((a0 + a1) + (a2 + a3)) * 0.125f;
  }
  __syncthreads();
  if (tid < 64) {
    float m0 = -1e30f, m1 = -1e30f, m2 = -1e30f, m3 = -1e30f;
#pragma unroll
    for (int j = 0; j < 64; j += 4) {
      m0 = fmaxf(m0, at[tid][j]); m1 = fmaxf(m1, at[tid][j + 1]);
      m2 = fmaxf(m2, at[tid][j + 2]); m3 = fmaxf(m3, at[tid][j + 3]);
    }
    const float m = fmaxf(fmaxf(m0, m1), fmaxf(m2, m3));
    float s0 = 0.f, s1 = 0.f, s2 = 0.f, s3 = 0.f;
#pragma unroll
    for (int j = 0; j < 64; j += 4) {
      const float e0 = __expf(at[tid][j] - m);
      const float e1 = __expf(at[tid][j + 1] - m);
      const float e2 = __expf(at[tid][j + 2] - m);
      const float e3 = __expf(at[tid][j + 3] - m);
      at[tid][j] = e0; at[tid][j + 1] = e1; at[tid][j + 2] = e2; at[tid][j + 3] = e3;
      s0 += e0; s1 += e1; s2 += e2; s3 += e3;
    }
    const float inv = 1.0f / ((s0 + s1) + (s2 + s3));
#pragma unroll
    for (int j = 0; j < 64; ++j) at[tid][j] *= inv;
  }
  __syncthreads();
  // out_s = attn @ v — ILP-4; write to outS scratch
  for (int cc = 0; cc < 16; ++cc) {
    const int c = w * 16 + cc;
    float a0 = 0.f, a1 = 0.f, a2 = 0.f, a3 = 0.f;
#pragma unroll
    for (int j = 0; j < 64; j += 4) {
      a0 = fmaf(at[lane][j], vv[j][c], a0);
      a1 = fmaf(at[lane][j + 1], vv[j + 1][c], a1);
      a2 = fmaf(at[lane][j + 2], vv[j + 2][c], a2);
      a3 = fmaf(at[lane][j + 3], vv[j + 3][c], a3);
    }
    outS[((long)bh * 64 + lane) * 64 + c] = (a0 + a1) + (a2 + a3);
  }
}

// ---------------------------------------------------------------- MT build (parallel, ILP-4):
// MT[b*256+d][h*64+g] = sum_c outS[((b*8+h)*64+g)*64+c] * Wo[d*512+h*64+c]
__global__ __launch_bounds__(256)
void mt_build_kernel(const float* __restrict__ outS, const float* __restrict__ Wo,
                     unsigned short* __restrict__ MT) {
  const int bd = blockIdx.x;   // b*256 + d
  const int b = bd >> 8;
  const int d = bd & 255;
  const int tid = threadIdx.x;
#pragma unroll
  for (int it = 0; it < 2; ++it) {
    const int hg = it * 256 + tid;
    const int h = hg >> 6;
    const int g = hg & 63;
    const float* wor = Wo + (long)d * 512 + h * 64;
    const float* os = outS + ((long)(b * 8 + h) * 64 + g) * 64;
    float a0 = 0.f, a1 = 0.f, a2 = 0.f, a3 = 0.f;
#pragma unroll
    for (int c = 0; c < 64; c += 4) {
      a0 = fmaf(os[c], wor[c], a0);
      a1 = fmaf(os[c + 1], wor[c + 1], a1);
      a2 = fmaf(os[c + 2], wor[c + 2], a2);
      a3 = fmaf(os[c + 3], wor[c + 3], a3);
    }
    MT[((long)b * 256 + d) * 512 + hg] = f2bu((a0 + a1) + (a2 + a3));
  }
}

// ---------------------------------------------------------------- launch
extern "C" void kernel_launch(void* const* d_in, const int* in_sizes, int n_in,
                              void* d_out, int out_size, void* d_ws, size_t ws_size,
                              hipStream_t stream) {
  const float* x = (const float*)d_in[0];
  const float* Wx = (const float*)d_in[1];
  const float* bx = (const float*)d_in[2];
  const float* W1 = (const float*)d_in[3];
  const float* b1 = (const float*)d_in[4];
  const float* W2 = (const float*)d_in[5];
  const float* b2 = (const float*)d_in[6];
  const float* bias = (const float*)d_in[7];
  const float* Ws = (const float*)d_in[8];
  const float* bs = (const float*)d_in[9];
  const float* Wq = (const float*)d_in[10];
  const float* Wk = (const float*)d_in[11];
  const float* Wv = (const float*)d_in[12];
  const float* Wo = (const float*)d_in[13];
  const float* bo = (const float*)d_in[14];
  const float* u = (const float*)d_in[15];
  float* out = (float*)d_out;

  char* ws = (char*)d_ws;
  unsigned short* xmid = (unsigned short*)(ws + 0);           // 67108864 B
  unsigned short* wbf = (unsigned short*)(ws + 67108864);     // 67108864 B
  float* sacc = (float*)(ws + 134217728);                     // 524288 B
  float* snrm = (float*)(ws + 134742016);                     // 8192 B
  unsigned short* Wxb = (unsigned short*)(ws + 134750208);    // 262144 B
  unsigned short* MT = (unsigned short*)(ws + 135012352);     // 1048576 B
  unsigned short* WrB = (unsigned short*)(ws + 136060928);    // 16384 B
  float* pacc = (float*)(ws + 136077312);                     // 16777216 B
  float* pnrm = (float*)(ws + 152854528);                     // 262144 B
  float* outS = (float*)(ws + 153116672);                     // 524288 B

  cast_kernel<<<dim3(128), dim3(256), 0, stream>>>(Wx, Wxb, INNER_ * D_);
  prep_wrb_kernel<<<dim3(32), dim3(256), 0, stream>>>(W1, Ws, WrB);
  gemm_bt_kernel<0><<<dim3(512, 4, 1), dim3(256), 0, stream>>>(x, nullptr, Wxb, xmid, nullptr, bx);
  routing_fused_kernel<<<dim3(8192), dim3(256), 0, stream>>>(xmid, WrB, u, b1, W2, b2, bias, bs, wbf);
  pool_v2_kernel<<<dim3(1024), dim3(256), 0, stream>>>(xmid, wbf, pacc, pnrm);
  pool_reduce_kernel<<<dim3(32), dim3(256), 0, stream>>>(pacc, pnrm, sacc, snrm);
  slice_attn_kernel<<<dim3(32), dim3(256), 0, stream>>>(sacc, snrm, Wq, Wk, Wv, outS);
  mt_build_kernel<<<dim3(1024), dim3(256), 0, stream>>>(outS, Wo, MT);
  gemm_bt_kernel<1><<<dim3(128, 2, 4), dim3(256), 0, stream>>>(nullptr, wbf, MT, nullptr, out, bo);
}